// Round 1
// baseline (349917.188 us; speedup 1.0000x reference)
//
#include <hip/hip_runtime.h>

#define TT 16384
#define HID 256
#define EMBD 16
#define TMPD 128
#define VOC 2048

typedef unsigned long long u64;
typedef unsigned int u32;

// workspace layout (bytes)
#define U_OFF_B    0ull                      // 16384*128*4 = 8 MiB
#define C_OFF_B    8388608ull                // 2048*128*4  = 1 MiB

// ---------------------------------------------------------------------------
// Phase A: U[t] = b1 + W1[:, :256] @ x_t   (blocks 0..TT-1)
//          C[i] = W1[:, 256:272] @ emb[i]  (blocks TT..TT+VOC-1)
// ---------------------------------------------------------------------------
__global__ __launch_bounds__(128) void prep_kernel(
    const float* __restrict__ x, const float* __restrict__ emb,
    const float* __restrict__ W1, const float* __restrict__ b1,
    float* __restrict__ U, float* __restrict__ C)
{
  const int b = blockIdx.x;
  const int j = threadIdx.x;   // 0..127 = output feature
  if (b < TT) {
    __shared__ __align__(16) float xs[HID];
    if (j < HID / 4) ((float4*)xs)[j] = ((const float4*)(x + (size_t)b * HID))[j];
    __syncthreads();
    float acc = b1[j];
    const float4* wr = (const float4*)(W1 + (size_t)j * (HID + EMBD)); // 1088B rows, 16B aligned
    #pragma unroll 8
    for (int c = 0; c < HID / 4; ++c) {
      float4 w = wr[c];
      acc = fmaf(xs[4 * c + 0], w.x, acc);
      acc = fmaf(xs[4 * c + 1], w.y, acc);
      acc = fmaf(xs[4 * c + 2], w.z, acc);
      acc = fmaf(xs[4 * c + 3], w.w, acc);
    }
    U[(size_t)b * TMPD + j] = acc;
  } else {
    const int e = b - TT;
    const float* er = emb + (size_t)e * EMBD;
    const float* wr = W1 + (size_t)j * (HID + EMBD) + HID;
    float acc = 0.f;
    #pragma unroll
    for (int k = 0; k < EMBD; ++k) acc = fmaf(er[k], wr[k], acc);
    C[(size_t)e * TMPD + j] = acc;
  }
}

// ---------------------------------------------------------------------------
// Phase B: ONE workgroup, 1024 threads, entire W2 register-resident
// (2 rows x 128 f32 = 256 VGPRs/thread; 4 waves/SIMD x ~310 VGPR < 2048 pool).
// No cross-workgroup communication: the per-step argmax + sumexp reduction is
// wave shuffle-reduce -> 16 leader LDS atomics (ds_max_u64 / ds_add_f32) onto
// a parity-double-buffered cell -> one barrier. Two __syncthreads per step.
// U[t+1] prefetched into a register one step ahead (hides the cold HBM line).
// Nontemporal U loads / out0 stores keep C (1 MiB) resident in this XCD's L2.
// ---------------------------------------------------------------------------
__global__ __launch_bounds__(1024, 1) void seq_kernel(
    const float* __restrict__ emb, const float* __restrict__ W2,
    const float* __restrict__ b2v, const int* __restrict__ init_idx,
    const float* __restrict__ U, const float* __restrict__ C,
    float* __restrict__ out0, float* __restrict__ out1,
    float* __restrict__ out2)
{
  const int tid = threadIdx.x;
  const int r0 = tid;           // rows tid and tid+1024
  const int r1 = tid + 1024;

  // W2 rows -> 256 VGPRs (all indices compile-time after unroll)
  float w0[TMPD], w1[TMPD];
  {
    const float4* a = (const float4*)(W2 + (size_t)r0 * TMPD); // 512B rows, aligned
    const float4* b = (const float4*)(W2 + (size_t)r1 * TMPD);
    #pragma unroll
    for (int c = 0; c < TMPD / 4; ++c) {
      float4 v = a[c];
      w0[4 * c + 0] = v.x; w0[4 * c + 1] = v.y; w0[4 * c + 2] = v.z; w0[4 * c + 3] = v.w;
      float4 u = b[c];
      w1[4 * c + 0] = u.x; w1[4 * c + 1] = u.y; w1[4 * c + 2] = u.z; w1[4 * c + 3] = u.w;
    }
  }
  const float br0 = b2v[r0];
  const float br1 = b2v[r1];

  __shared__ __align__(16) float hbuf[TMPD];
  __shared__ u64   gkey[2];    // parity-double-buffered reduction cells
  __shared__ float gsum[2];

  if (tid == 0) { gkey[0] = 0ull; gsum[0] = 0.f; }  // ordered before barrier#1(t=0)

  int cur = init_idx[0];
  float upf = 0.f;
  if (tid < TMPD) upf = __builtin_nontemporal_load(U + tid);   // U[0] prefetch

  for (int t = 0; t < TT; ++t) {
    const int pc = t & 1;

    // ---- h = lrelu(U[t] + C[cur]) -> LDS; issue U[t+1] prefetch ----
    if (tid < TMPD) {
      float v = upf + C[(size_t)cur * TMPD + tid];
      hbuf[tid] = (v > 0.f) ? v : 0.01f * v;
      const int tn = (t + 1 < TT) ? (t + 1) : t;
      upf = __builtin_nontemporal_load(U + (size_t)tn * TMPD + tid);
    }
    __syncthreads();                                   // barrier#1

    // reset the OTHER parity cell for step t+1.
    // last readers of cell[pc^1] were in tail of step t-1 (before barrier#1(t));
    // its next atomics are at step t+1 (after barrier#1(t+1)). Race-free.
    if (tid == 0) { gkey[pc ^ 1] = 0ull; gsum[pc ^ 1] = 0.f; }

    // ---- logits: 2 rows/thread, h broadcast from LDS ----
    float a0 = br0, a1 = br1;
    #pragma unroll
    for (int k0 = 0; k0 < TMPD; k0 += 4) {
      float4 hv = *(const float4*)(hbuf + k0);         // broadcast ds_read_b128
      a0 = fmaf(w0[k0 + 0], hv.x, a0);
      a0 = fmaf(w0[k0 + 1], hv.y, a0);
      a0 = fmaf(w0[k0 + 2], hv.z, a0);
      a0 = fmaf(w0[k0 + 3], hv.w, a0);
      a1 = fmaf(w1[k0 + 0], hv.x, a1);
      a1 = fmaf(w1[k0 + 1], hv.y, a1);
      a1 = fmaf(w1[k0 + 2], hv.z, a1);
      a1 = fmaf(w1[k0 + 3], hv.w, a1);
    }

    // ---- ordered keys (argmax, first-index tie-break) + sumexp ----
    float s = __expf(a0) + __expf(a1);
    u32 f0 = __float_as_uint(a0);
    u32 o0 = (f0 & 0x80000000u) ? ~f0 : (f0 | 0x80000000u);
    u32 f1 = __float_as_uint(a1);
    u32 o1 = (f1 & 0x80000000u) ? ~f1 : (f1 | 0x80000000u);
    u64 k0_ = ((u64)o0 << 32) | (u32)(2047 - r0);
    u64 k1_ = ((u64)o1 << 32) | (u32)(2047 - r1);
    u64 kk = (k1_ > k0_) ? k1_ : k0_;

    #pragma unroll
    for (int off = 32; off > 0; off >>= 1) {           // wave64 down-reduce
      u64 ok = __shfl_down(kk, off);
      float os = __shfl_down(s, off);
      s += os;
      if (ok > kk) kk = ok;
    }
    if ((tid & 63) == 0) {                             // 16 wave leaders
      atomicMax(&gkey[pc], kk);
      atomicAdd(&gsum[pc], s);
    }
    __syncthreads();                                   // barrier#2

    const u64 best = gkey[pc];
    const float St = gsum[pc];
    const int nidx = 2047 - (int)(best & 0xFFFFull);
    const float lgS = __logf(St);

    __builtin_nontemporal_store(a0 - lgS, out0 + (size_t)t * VOC + r0);
    __builtin_nontemporal_store(a1 - lgS, out0 + (size_t)t * VOC + r1);
    if (tid < EMBD) out1[(size_t)t * EMBD + tid] = emb[(size_t)nidx * EMBD + tid];
    if (tid == 1023) out2[t] = (float)nidx;
    cur = nidx;
  }
}

// ---------------------------------------------------------------------------
extern "C" void kernel_launch(void* const* d_in, const int* in_sizes, int n_in,
                              void* d_out, int out_size, void* d_ws, size_t ws_size,
                              hipStream_t stream) {
  const float* x    = (const float*)d_in[0];   // [16384,256] f32
  const float* emb  = (const float*)d_in[1];   // [2048,16]   f32
  const float* W1   = (const float*)d_in[2];   // [128,272]   f32
  const float* b1   = (const float*)d_in[3];   // [128]       f32
  const float* W2   = (const float*)d_in[4];   // [2048,128]  f32
  const float* b2v  = (const float*)d_in[5];   // [2048]      f32
  const int*   init = (const int*)d_in[6];     // scalar int

  float* U = (float*)((char*)d_ws + U_OFF_B);
  float* C = (float*)((char*)d_ws + C_OFF_B);

  float* out0 = (float*)d_out;                                        // [T, 2048]
  float* out1 = (float*)d_out + (size_t)TT * VOC;                     // [T, 1, 16]
  float* out2 = (float*)d_out + (size_t)TT * VOC + (size_t)TT * EMBD; // [T]

  hipLaunchKernelGGL(prep_kernel, dim3(TT + VOC), dim3(128), 0, stream,
                     x, emb, W1, b1, U, C);
  hipLaunchKernelGGL(seq_kernel, dim3(1), dim3(1024), 0, stream,
                     emb, W2, b2v, init, U, C, out0, out1, out2);
}

// Round 3
// 60647.400 us; speedup vs baseline: 5.7697x; 5.7697x over previous
//
#include <hip/hip_runtime.h>

#define TT 16384
#define HID 256
#define EMBD 16
#define TMPD 128
#define VOC 2048
#define NB 32    // seq blocks launched; pigeonhole over 8 XCDs guarantees >=4 on one XCD
#define NW 4     // workers

typedef unsigned long long u64;
typedef unsigned int u32;
typedef __attribute__((ext_vector_type(2))) unsigned long long ull2;

// workspace layout (bytes)
#define U_OFF_B      0ull          // 16384*128*4 = 8 MiB
#define C_OFF_B      8388608ull    // 2048*128*4  = 1 MiB
#define SLOW_OFF_B   9437184ull    // TT * 64B  (4 workers x 2 u64, agent-scope slots)
#define FAST_OFF_B  10485760ull    // TT * 64B  (4 workers x 16B, same-XCD L2 slots)
#define HSLOW_OFF_B 11534336ull    // 4 x u64 hello (slow)
#define HFAST_OFF_B 11534464ull    // 64B hello (fast)
#define MAIL_OFF_B  11534592ull    // NB x u32 election mailboxes

// sc0 = SE scope: bypass per-CU L1, execute at the XCD's shared L2.
__device__ __forceinline__ void st64_sc0(void* p, u64 v) {
  asm volatile("global_store_dwordx2 %0, %1, off sc0"
               :: "v"((u64)(uintptr_t)p), "v"(v) : "memory");
}
__device__ __forceinline__ ull2 ld128_sc0(const void* p) {
  ull2 r;
  asm volatile("global_load_dwordx4 %0, %1, off sc0\n\ts_waitcnt vmcnt(0)"
               : "=v"(r) : "v"((u64)(uintptr_t)p) : "memory");
  return r;
}
// 21-bit self-validating tag: mixes step + per-run nonce, bit20 always set
// (0x00000000 and 0xAA..AA poison both fail the check).
__device__ __forceinline__ u32 mktag(u32 t, u32 n) {
  return (((t ^ (n << 4)) & 0xFFFFFu) | 0x100000u);
}

// ---------------------------------------------------------------------------
// Phase A: U[t] = b1 + W1[:, :256] @ x_t   (blocks 0..TT-1)
//          C[i] = W1[:, 256:272] @ emb[i]  (blocks TT..TT+VOC-1)
// Also re-inits slow slots (~0 sentinel), fast slots (0), hellos, mailboxes.
// Kernel-boundary L2 writeback/invalidate makes these visible to seq (round-0
// empirically proven for the slow-slot sentinel protocol).
// ---------------------------------------------------------------------------
__global__ __launch_bounds__(128) void prep_kernel(
    const float* __restrict__ x, const float* __restrict__ emb,
    const float* __restrict__ W1, const float* __restrict__ b1,
    float* __restrict__ U, float* __restrict__ C,
    u64* __restrict__ slow, u64* __restrict__ fastq,
    u64* __restrict__ hslow, u64* __restrict__ hfast, u32* __restrict__ mail)
{
  const int b = blockIdx.x;
  const int j = threadIdx.x;   // 0..127 = output feature
  if (b < TT) {
    if (j < 8)               slow[(size_t)b * 8 + j] = ~0ull;       // fails BEEF/C0DE
    else if (j < 16)         fastq[(size_t)b * 8 + (j - 8)] = 0ull; // fails bit20 tag
    __shared__ __align__(16) float xs[HID];
    if (j < HID / 4) ((float4*)xs)[j] = ((const float4*)(x + (size_t)b * HID))[j];
    __syncthreads();
    float acc = b1[j];
    const float4* wr = (const float4*)(W1 + (size_t)j * (HID + EMBD)); // 1088B rows, 16B aligned
    #pragma unroll 8
    for (int c = 0; c < HID / 4; ++c) {
      float4 w = wr[c];
      acc = fmaf(xs[4 * c + 0], w.x, acc);
      acc = fmaf(xs[4 * c + 1], w.y, acc);
      acc = fmaf(xs[4 * c + 2], w.z, acc);
      acc = fmaf(xs[4 * c + 3], w.w, acc);
    }
    U[(size_t)b * TMPD + j] = acc;
  } else {
    const int e = b - TT;
    if (e == 0) {
      if (j < NB) mail[j] = 0u;
      if (j >= 32 && j < 36) hslow[j - 32] = ~0ull;
      if (j >= 40 && j < 48) hfast[j - 40] = 0ull;
    }
    const float* er = emb + (size_t)e * EMBD;
    const float* wr = W1 + (size_t)j * (HID + EMBD) + HID;
    float acc = 0.f;
    #pragma unroll
    for (int k = 0; k < EMBD; ++k) acc = fmaf(er[k], wr[k], acc);
    C[(size_t)e * TMPD + j] = acc;
  }
}

// ---------------------------------------------------------------------------
// Phase B: 32 blocks x 512 threads. Election picks the first XCD with >=4
// blocks (pigeonhole-guaranteed); those 4 become workers (rows wid*512+tid,
// one W2 row = 128 f32 volatile-pinned VGPRs/thread; launch_bounds(512,2)
// caps VGPR at 256 so no scratch). 28 losers exit.
// Per step: intra-block reduce (wave shfl -> LDS atomics on parity cells),
// then publish BOTH a fast packet (sc0 -> shared XCD L2) and a slow packet
// (agent atomics, round-0 format). Poll fast (tag-validated, hello-verified,
// clock-bounded sticky fallback) else slow. Guaranteed termination either way.
// ---------------------------------------------------------------------------
__global__ __launch_bounds__(512, 2) void seq_kernel(
    const float* __restrict__ emb, const float* __restrict__ W2,
    const float* __restrict__ b2v, const int* __restrict__ init_idx,
    const float* __restrict__ U, const float* __restrict__ C,
    u64* slow, u64* fastq, u64* hslow, u64* hfast, u32* mail,
    float* __restrict__ out0, float* __restrict__ out1,
    float* __restrict__ out2)
{
  const int tid = threadIdx.x;
  __shared__ int s_wid;
  __shared__ u32 s_nonce;
  __shared__ int s_fast;
  __shared__ __align__(16) float hbuf[TMPD];
  __shared__ u64   gkey[2];
  __shared__ float gsum[2];

  // ---- one-time election (tid 0; round-0-proven agent-atomic mailboxes) ----
  if (tid == 0) {
    u32 xcc = 0;
    asm volatile("s_getreg_b32 %0, hwreg(HW_REG_XCC_ID)" : "=s"(xcc));
    xcc &= 7u;
    u32 nb = 0x100u | xcc;
    if (blockIdx.x == 0) {                     // block 0 carries the run nonce
      u64 ck = (u64)clock64();
      nb |= ((u32)((ck >> 2) & 0x7FFFull)) << 16;
    }
    __hip_atomic_store(&mail[blockIdx.x], nb, __ATOMIC_RELAXED, __HIP_MEMORY_SCOPE_AGENT);
    u32 mm[NB];
    for (;;) {
      bool ok = true;
      for (int q = 0; q < NB; ++q) {
        mm[q] = __hip_atomic_load(&mail[q], __ATOMIC_RELAXED, __HIP_MEMORY_SCOPE_AGENT);
        ok &= (mm[q] & 0x100u) != 0u;
      }
      if (ok) break;
    }
    int cnt[8] = {0, 0, 0, 0, 0, 0, 0, 0};
    for (int q = 0; q < NB; ++q) cnt[mm[q] & 7]++;
    int excd = 0;
    for (int xx = 0; xx < 8; ++xx) if (cnt[xx] >= NW) { excd = xx; break; } // guaranteed
    int pick[NW]; int np = 0;
    for (int q = 0; q < NB && np < NW; ++q)
      if ((int)(mm[q] & 7) == excd) pick[np++] = q;
    int me = -1;
    for (int i = 0; i < NW; ++i) if (pick[i] == (int)blockIdx.x) me = i;
    s_wid = me;
    s_nonce = ((mm[0] >> 16) & 0x7FFFu) | 0x8000u;
  }
  __syncthreads();
  const int wid = s_wid;
  if (wid < 0) return;                                 // 28 losers exit
  const u32 nonce = s_nonce;

  // ---- W2 row -> 128 VGPRs; volatile pins against remat/reload ----
  const int grow = wid * 512 + tid;                    // global row 0..2047
  float w[TMPD];
  {
    const volatile float* a = W2 + (size_t)grow * TMPD;
    #pragma unroll
    for (int c = 0; c < TMPD; ++c) w[c] = a[c];
  }
  const float br = b2v[grow];

  // ---- hello handshake: verify the fast (same-L2) path actually works ----
  char* hfc = (char*)hfast;
  {
    const u32 et = 0x7ABCu;
    const u32 htag = mktag(et, nonce);
    const u32 htw1 = (et << 16) | nonce;
    if (tid == 0) {
      st64_sc0(hfc + wid * 16 + 0, (u64)htag);
      st64_sc0(hfc + wid * 16 + 8, (u64)htw1);
    }
    if (tid == 64)
      __hip_atomic_store(&hslow[wid], 0x600DF00Dull, __ATOMIC_RELAXED, __HIP_MEMORY_SCOPE_AGENT);
    for (;;) {                                         // guaranteed: 4 workers resident
      bool ok = true;
      #pragma unroll
      for (int p = 0; p < NW; ++p)
        ok &= (__hip_atomic_load(&hslow[p], __ATOMIC_RELAXED, __HIP_MEMORY_SCOPE_AGENT)
               == 0x600DF00Dull);
      if (ok) break;
    }
    if (tid == 0) {
      long long t0 = clock64();
      int okf = 0;
      for (;;) {
        int seen = 0;
        #pragma unroll
        for (int p = 0; p < NW; ++p) {
          ull2 f = ld128_sc0(hfc + p * 16);
          seen += (((u32)f[0] & 0x1FFFFFu) == htag) && ((u32)f[1] == htw1);
        }
        if (seen == NW) { okf = 1; break; }
        if (clock64() - t0 > 5000000LL) break;         // ~2 ms: fast path dead
      }
      s_fast = okf;
      gkey[0] = 0ull; gsum[0] = 0.f;
    }
  }
  __syncthreads();
  bool fastp = (s_fast != 0);

  int cur = init_idx[0];
  float upf = (tid < TMPD) ? U[tid] : 0.f;
  char* fastc = (char*)fastq;

  for (int t = 0; t < TT; ++t) {
    const int pc = t & 1;

    // ---- h = lrelu(U[t] + C[cur]) -> LDS; issue U[t+1] prefetch ----
    if (tid < TMPD) {
      float v = upf + C[(size_t)cur * TMPD + tid];
      hbuf[tid] = (v > 0.f) ? v : 0.01f * v;
      const int tn = (t + 1 < TT) ? (t + 1) : t;
      upf = U[(size_t)tn * TMPD + tid];
    }
    __syncthreads();                                   // barrier#1
    if (tid == 0) { gkey[pc ^ 1] = 0ull; gsum[pc ^ 1] = 0.f; }

    // ---- logit: 1 row/thread, h broadcast from LDS (round-0 fma chain) ----
    float acc = br;
    #pragma unroll
    for (int k0 = 0; k0 < TMPD; k0 += 4) {
      float4 hv = *(const float4*)(hbuf + k0);         // broadcast ds_read_b128
      acc = fmaf(w[k0 + 0], hv.x, acc);
      acc = fmaf(w[k0 + 1], hv.y, acc);
      acc = fmaf(w[k0 + 2], hv.z, acc);
      acc = fmaf(w[k0 + 3], hv.w, acc);
    }

    // ---- ordered key (argmax, first-index tie-break) + sumexp ----
    float s = __expf(acc);
    u32 fb  = __float_as_uint(acc);
    u32 ord = (fb & 0x80000000u) ? ~fb : (fb | 0x80000000u);
    u64 kk  = ((u64)ord << 32) | (u32)(2047 - grow);
    #pragma unroll
    for (int off = 32; off > 0; off >>= 1) {           // wave64 down-reduce
      u64 ok = __shfl_down(kk, off);
      float os = __shfl_down(s, off);
      s += os;
      if (ok > kk) kk = ok;
    }
    if ((tid & 63) == 0) {                             // 8 wave leaders
      atomicMax(&gkey[pc], kk);
      atomicAdd(&gsum[pc], s);
    }
    __syncthreads();                                   // barrier#2

    const u64   K = gkey[pc];
    const float S = gsum[pc];
    const u32 tag21 = mktag((u32)t, nonce);
    const u32 tw1   = ((u32)t << 16) | nonce;
    u64*  slw = slow + (size_t)t * 8;
    char* fl  = fastc + (size_t)t * 64;

    if (tid == 64) {   // wave1 leader: slow publish (keeps wave0 vmcnt clean)
      u64 hi = K & 0xFFFFFFFF00000000ull;
      __hip_atomic_store(slw + wid * 2 + 0, hi | ((K & 0xFFFFull) << 16) | 0xBEEFull,
                         __ATOMIC_RELAXED, __HIP_MEMORY_SCOPE_AGENT);
      __hip_atomic_store(slw + wid * 2 + 1, ((u64)__float_as_uint(S) << 32) | 0xC0DEull,
                         __ATOMIC_RELAXED, __HIP_MEMORY_SCOPE_AGENT);
    }
    if (tid == 0) {    // fast publish into the shared-XCD L2
      u64 hi = K & 0xFFFFFFFF00000000ull;
      st64_sc0(fl + wid * 16 + 0, hi | ((K & 0x7FFull) << 21) | (u64)tag21);
      st64_sc0(fl + wid * 16 + 8, ((u64)__float_as_uint(S) << 32) | (u64)tw1);
    }

    // ---- gather the other 3 partials (all threads; uniform values) ----
    u64 kbest = K;
    float Sarr[NW];
    #pragma unroll
    for (int i = 0; i < NW; ++i) Sarr[i] = (i == wid) ? S : 0.f;   // static idx only
    u32 need = 0xFu & ~(1u << wid);

    if (fastp) {
      long long t0 = clock64();
      while (need) {
        #pragma unroll
        for (int p = 0; p < NW; ++p) if (need & (1u << p)) {
          ull2 f = ld128_sc0(fl + p * 16);
          if (((u32)f[0] & 0x1FFFFFu) == tag21 && (u32)f[1] == tw1) {
            u64 kp = (f[0] & 0xFFFFFFFF00000000ull) | ((f[0] >> 21) & 0x7FFull);
            if (kp > kbest) kbest = kp;
            Sarr[p] = __uint_as_float((u32)(f[1] >> 32));
            need &= ~(1u << p);
          }
        }
        if (need && (clock64() - t0 > 30000000LL)) { fastp = false; break; }
      }
    }
    while (need) {                                     // always-correct slow path
      #pragma unroll
      for (int p = 0; p < NW; ++p) if (need & (1u << p)) {
        u64 a = __hip_atomic_load(slw + p * 2 + 0, __ATOMIC_RELAXED, __HIP_MEMORY_SCOPE_AGENT);
        u64 b = __hip_atomic_load(slw + p * 2 + 1, __ATOMIC_RELAXED, __HIP_MEMORY_SCOPE_AGENT);
        if ((a & 0xFFFFull) == 0xBEEFull && ((a >> 16) & 0xFFFFull) <= 2047ull &&
            (b & 0xFFFFFFFFull) == 0xC0DEull) {
          u64 kp = (a & 0xFFFFFFFF00000000ull) | ((a >> 16) & 0xFFFFull);
          if (kp > kbest) kbest = kp;
          Sarr[p] = __uint_as_float((u32)(b >> 32));
          need &= ~(1u << p);
        }
      }
    }

    const float St  = ((Sarr[0] + Sarr[1]) + Sarr[2]) + Sarr[3];  // fixed order
    const int  nidx = 2047 - (int)(kbest & 0xFFFFull);
    const float lgS = __logf(St);

    __builtin_nontemporal_store(acc - lgS, out0 + (size_t)t * VOC + grow);
    if (wid == 0) {
      if (tid < EMBD) out1[(size_t)t * EMBD + tid] = emb[(size_t)nidx * EMBD + tid];
      if (tid == 32)  out2[t] = (float)nidx;
    }
    cur = nidx;
  }
}

// ---------------------------------------------------------------------------
extern "C" void kernel_launch(void* const* d_in, const int* in_sizes, int n_in,
                              void* d_out, int out_size, void* d_ws, size_t ws_size,
                              hipStream_t stream) {
  const float* x    = (const float*)d_in[0];   // [16384,256] f32
  const float* emb  = (const float*)d_in[1];   // [2048,16]   f32
  const float* W1   = (const float*)d_in[2];   // [128,272]   f32
  const float* b1   = (const float*)d_in[3];   // [128]       f32
  const float* W2   = (const float*)d_in[4];   // [2048,128]  f32
  const float* b2v  = (const float*)d_in[5];   // [2048]      f32
  const int*   init = (const int*)d_in[6];     // scalar int

  float* U     = (float*)((char*)d_ws + U_OFF_B);
  float* C     = (float*)((char*)d_ws + C_OFF_B);
  u64*   slow  = (u64*)((char*)d_ws + SLOW_OFF_B);
  u64*   fastq = (u64*)((char*)d_ws + FAST_OFF_B);
  u64*   hslow = (u64*)((char*)d_ws + HSLOW_OFF_B);
  u64*   hfast = (u64*)((char*)d_ws + HFAST_OFF_B);
  u32*   mail  = (u32*)((char*)d_ws + MAIL_OFF_B);

  float* out0 = (float*)d_out;                                        // [T, 2048]
  float* out1 = (float*)d_out + (size_t)TT * VOC;                     // [T, 1, 16]
  float* out2 = (float*)d_out + (size_t)TT * VOC + (size_t)TT * EMBD; // [T]

  hipLaunchKernelGGL(prep_kernel, dim3(TT + VOC), dim3(128), 0, stream,
                     x, emb, W1, b1, U, C, slow, fastq, hslow, hfast, mail);
  hipLaunchKernelGGL(seq_kernel, dim3(NB), dim3(512), 0, stream,
                     emb, W2, b2v, init, U, C, slow, fastq, hslow, hfast, mail,
                     out0, out1, out2);
}